// Round 10
// baseline (76.162 us; speedup 1.0000x reference)
//
#include <hip/hip_runtime.h>
#include <hip/hip_bf16.h>

#define M_DIM 8192
#define N_DIM 8192

typedef short short8 __attribute__((ext_vector_type(8)));
typedef float f32x4 __attribute__((ext_vector_type(4)));

static __device__ __forceinline__ short f2bf(float f) {
    __hip_bfloat16 h = __float2bfloat16(f);   // RNE convert
    union { __hip_bfloat16 h; short s; } u;
    u.h = h;
    return u.s;
}

// Fused single kernel: C[m,n] = dq[m,:] @ act[:,n].
// PIPELINED-PERSISTENT (R8 skeleton): grid 512 (2 blocks/CU, zero tail), bn
// fixed per block, B fragments built once from f32 act, M-walk with B-reuse,
// no block barriers, fire-and-forget NT stores overlap next tile's dequant.
// R10: wave owns 32 rows x 256 cols (block 128x256, 4 M-tiles). One store
// instruction = 64 lanes x 16B = a full 1KB contiguous row segment (R7: 128B,
// R8: 512B -> 59 -> 51 us; this continues the only lever that has worked).
// acc kept at 8 fragments (32 VGPR) via two compute/stage sub-phases per
// 16-row slab; peak ~190 VGPR, no spills.
__global__ __launch_bounds__(256, 2) void gemm_dq(const float* __restrict__ scale,
                                                  const int* __restrict__ offset,
                                                  const int* __restrict__ weight,
                                                  const float* __restrict__ act,
                                                  float* __restrict__ C) {
    // wave-private staging: 16 rows x 260 cols f32 (pad 4 -> 2-way conflicts max)
    __shared__ float cs[4][16 * 260];

    const int tid  = threadIdx.x;
    const int lane = tid & 63;
    const int wid  = tid >> 6;
    const int l15  = lane & 15;
    const int l4   = lane >> 4;

    const int bn = (int)blockIdx.x & 31;      // 32 n-tiles of 256
    const int mg = (int)blockIdx.x >> 5;      // 16 m-groups of 4 tiles (512 rows)
    const int n0 = bn * 256;                  // block's 256-col extent

    // ---- B fragments: built ONCE from act [64, 8192] f32 (L2/L3-hot),
    // converted to bf16 in-register; reused across 4 m-tiles (128 VGPR).
    // Element j of fragment (kh,fn) = act[kh*32 + l4*8 + j][n0 + fn*16 + l15].
    short8 bfrag[2][16];
    #pragma unroll
    for (int kh = 0; kh < 2; ++kh) {
        #pragma unroll
        for (int fn = 0; fn < 16; ++fn) {
            const float* ap = act + (size_t)(kh * 32 + l4 * 8) * N_DIM + (n0 + fn * 16 + l15);
            short8 b;
            #pragma unroll
            for (int j = 0; j < 8; ++j) {
                b[j] = f2bf(ap[(size_t)j * N_DIM]);
            }
            bfrag[kh][fn] = b;
        }
    }

    float* ws = &cs[wid][0];
    const int rot = ((mg >> 3) & 1) * 2;      // desync co-resident block pair

    for (int ti = 0; ti < 4; ++ti) {
        const int t  = (ti + rot) & 3;
        const int m0 = mg * 512 + t * 128 + wid * 32;   // wave's 32-row slab

        // ---- Two 16-row slabs per tile (keeps acc live-set at 32 VGPR).
        #pragma unroll
        for (int fm = 0; fm < 2; ++fm) {
            // A fragments: dequantize 4-bit weights directly into registers.
            // Lane: row m = m0+fm*16+(lane&15), k = kh*32+(lane>>4)*8+j
            // => group g = kh*4+l4: one word, one scale, one offset nibble.
            short8 afrag[2];
            #pragma unroll
            for (int kh = 0; kh < 2; ++kh) {
                const int g = kh * 4 + l4;
                const int m = m0 + fm * 16 + l15;
                const unsigned w = (unsigned)weight[m * 8 + g];
                const float   s = scale[m * 8 + g];
                const int   off = (int)(((unsigned)offset[m] >> (4 * g)) & 15u);
                short8 a;
                #pragma unroll
                for (int j = 0; j < 8; ++j) {
                    const int wv = (int)((w >> (4 * j)) & 15u);
                    a[j] = f2bf(s * (float)(wv - off));
                }
                afrag[kh] = a;
            }

            // Compute + stage in two sub-phases of 8 fn-fragments each.
            #pragma unroll
            for (int h = 0; h < 2; ++h) {
                f32x4 acc[8] = {};
                #pragma unroll
                for (int f = 0; f < 8; ++f) {
                    const int fn = h * 8 + f;
                    acc[f] = __builtin_amdgcn_mfma_f32_16x16x32_bf16(
                        afrag[0], bfrag[0][fn], acc[f], 0, 0, 0);
                    acc[f] = __builtin_amdgcn_mfma_f32_16x16x32_bf16(
                        afrag[1], bfrag[1][fn], acc[f], 0, 0, 0);
                }
                // Stage 16x128 half into padded LDS.
                // C/D layout: col = fn*16 + l15, row16 = l4*4 + j.
                #pragma unroll
                for (int f = 0; f < 8; ++f) {
                    const int col = (h * 8 + f) * 16 + l15;
                    #pragma unroll
                    for (int j = 0; j < 4; ++j) {
                        const int row16 = l4 * 4 + j;
                        ws[row16 * 260 + col] = acc[f][j];
                    }
                }
            }
            // wave-internal RAW on LDS (per-wave DS pipe is in-order)
            asm volatile("s_waitcnt lgkmcnt(0)" ::: "memory");

            // Store: ONE instruction per row = 64 lanes x 16B = 1KB contiguous.
            #pragma unroll
            for (int r = 0; r < 16; ++r) {
                const f32x4 v = *reinterpret_cast<const f32x4*>(&ws[r * 260 + lane * 4]);
                const size_t gr = (size_t)(m0 + fm * 16 + r);
                __builtin_nontemporal_store(v, reinterpret_cast<f32x4*>(
                    &C[gr * N_DIM + n0 + lane * 4]));
            }
        }
    }
}

extern "C" void kernel_launch(void* const* d_in, const int* in_sizes, int n_in,
                              void* d_out, int out_size, void* d_ws, size_t ws_size,
                              hipStream_t stream) {
    const float* scale  = (const float*)d_in[0];
    const int*   offset = (const int*)d_in[1];
    const int*   weight = (const int*)d_in[2];
    const float* act    = (const float*)d_in[3];
    float* out  = (float*)d_out;

    gemm_dq<<<512, 256, 0, stream>>>(scale, offset, weight, act, out);
}

// Round 11
// 49.822 us; speedup vs baseline: 1.5287x; 1.5287x over previous
//
#include <hip/hip_runtime.h>
#include <hip/hip_bf16.h>

#define M_DIM 8192
#define N_DIM 8192

typedef short short8 __attribute__((ext_vector_type(8)));
typedef float f32x4 __attribute__((ext_vector_type(4)));

static __device__ __forceinline__ short f2bf(float f) {
    __hip_bfloat16 h = __float2bfloat16(f);   // RNE convert
    union { __hip_bfloat16 h; short s; } u;
    u.h = h;
    return u.s;
}

// Fused single kernel: C[m,n] = dq[m,:] @ act[:,n].
// EXACT R8 STRUCTURE (51.1 us): grid 512 (2 blocks/CU, zero tail), bn fixed
// per block, B fragments built once from f32 act, 8 M-tiles walked with no
// block barriers, fire-and-forget stores overlap next tile's dequant, wave
// owns 32 rows x 128 cols, 512B/row write bursts.
// R11 single-variable ablation: PLAIN stores instead of nontemporal. Theory:
// NT = no-allocate, so 512B chunks hit DRAM unaggregated; plain stores drain
// through L2's eviction engine in large address-sorted batches (the 7 TB/s
// fill kernels use plain stores).
__global__ __launch_bounds__(256, 2) void gemm_dq(const float* __restrict__ scale,
                                                  const int* __restrict__ offset,
                                                  const int* __restrict__ weight,
                                                  const float* __restrict__ act,
                                                  float* __restrict__ C) {
    // wave-private staging: 16 rows x 132 cols f32 (pad -> <=2-way conflicts)
    __shared__ float cs[4][16 * 132];

    const int tid  = threadIdx.x;
    const int lane = tid & 63;
    const int wid  = tid >> 6;
    const int l15  = lane & 15;
    const int l4   = lane >> 4;

    const int bn = (int)blockIdx.x & 63;      // 64 n-tiles of 128
    const int mg = (int)blockIdx.x >> 6;      // 8 m-groups of 8 tiles
    const int n0 = bn * 128;                  // block's 128-col extent

    // ---- B fragments: built ONCE from act [64, 8192] f32 (L2/L3-hot),
    // converted to bf16 in-register; reused across all 8 m-tiles.
    // Element j of fragment (kh,fn) = act[kh*32 + l4*8 + j][n0 + fn*16 + l15].
    short8 bfrag[2][8];
    #pragma unroll
    for (int kh = 0; kh < 2; ++kh) {
        #pragma unroll
        for (int fn = 0; fn < 8; ++fn) {
            const float* ap = act + (size_t)(kh * 32 + l4 * 8) * N_DIM + (n0 + fn * 16 + l15);
            short8 b;
            #pragma unroll
            for (int j = 0; j < 8; ++j) {
                b[j] = f2bf(ap[(size_t)j * N_DIM]);
            }
            bfrag[kh][fn] = b;
        }
    }

    float* ws = &cs[wid][0];
    const int rot = ((mg >> 2) & 1) * 4;      // desync co-resident block pair

    #pragma unroll 2
    for (int ti = 0; ti < 8; ++ti) {
        const int t  = (ti + rot) & 7;
        const int m0 = (mg * 8 + t) * 128 + wid * 32;   // wave's 32-row slab

        // ---- Process the wave's two 16-row fragments one at a time
        // (keeps acc live-set at 32 VGPR).
        #pragma unroll
        for (int fm = 0; fm < 2; ++fm) {
            // A fragments: dequantize 4-bit weights directly into registers.
            // Lane: row m = m0+fm*16+(lane&15), k = kh*32+(lane>>4)*8+j
            // => group g = kh*4+(lane>>4): one word, one scale, one offset nibble.
            short8 afrag[2];
            #pragma unroll
            for (int kh = 0; kh < 2; ++kh) {
                const int g = kh * 4 + l4;
                const int m = m0 + fm * 16 + l15;
                const unsigned w = (unsigned)weight[m * 8 + g];
                const float   s = scale[m * 8 + g];
                const int   off = (int)(((unsigned)offset[m] >> (4 * g)) & 15u);
                short8 a;
                #pragma unroll
                for (int j = 0; j < 8; ++j) {
                    const int wv = (int)((w >> (4 * j)) & 15u);
                    a[j] = f2bf(s * (float)(wv - off));
                }
                afrag[kh] = a;
            }

            // MFMA: 16 rows x 128 cols = 8 fn-fragments x 2 k-halves
            f32x4 acc[8] = {};
            #pragma unroll
            for (int fn = 0; fn < 8; ++fn) {
                acc[fn] = __builtin_amdgcn_mfma_f32_16x16x32_bf16(
                    afrag[0], bfrag[0][fn], acc[fn], 0, 0, 0);
                acc[fn] = __builtin_amdgcn_mfma_f32_16x16x32_bf16(
                    afrag[1], bfrag[1][fn], acc[fn], 0, 0, 0);
            }

            // Stage 16x128 into padded LDS (2-way bank aliasing = free).
            // C/D layout: col = fn*16 + l15, row16 = l4*4 + j.
            #pragma unroll
            for (int fn = 0; fn < 8; ++fn) {
                const int col = fn * 16 + l15;
                #pragma unroll
                for (int j = 0; j < 4; ++j) {
                    const int row16 = l4 * 4 + j;
                    ws[row16 * 132 + col] = acc[fn][j];
                }
            }
            // wave-internal RAW on LDS (per-wave DS pipe is in-order)
            asm volatile("s_waitcnt lgkmcnt(0)" ::: "memory");

            // Readback + store: each instr = 2 rows x 512B contiguous; rows
            // ascend. PLAIN stores (R11 ablation: drain via L2 eviction engine).
            #pragma unroll
            for (int s = 0; s < 8; ++s) {
                const int row16 = s * 2 + (lane >> 5);
                const int c4    = (lane & 31) * 4;
                const f32x4 v = *reinterpret_cast<const f32x4*>(&ws[row16 * 132 + c4]);
                const size_t gr = (size_t)(m0 + fm * 16 + row16);
                *reinterpret_cast<f32x4*>(&C[gr * N_DIM + n0 + c4]) = v;
            }
        }
    }
}

extern "C" void kernel_launch(void* const* d_in, const int* in_sizes, int n_in,
                              void* d_out, int out_size, void* d_ws, size_t ws_size,
                              hipStream_t stream) {
    const float* scale  = (const float*)d_in[0];
    const int*   offset = (const int*)d_in[1];
    const int*   weight = (const int*)d_in[2];
    const float* act    = (const float*)d_in[3];
    float* out  = (float*)d_out;

    gemm_dq<<<512, 256, 0, stream>>>(scale, offset, weight, act, out);
}